// Round 12
// baseline (218.591 us; speedup 1.0000x reference)
//
#include <hip/hip_runtime.h>
#include <cstdint>
#include <cstddef>

// Problem constants: B=2, N=16384, K=32, F=64, E=16
#define LOGN 14

typedef __bf16 bf16x8 __attribute__((ext_vector_type(8)));
typedef float f32x4 __attribute__((ext_vector_type(4)));
typedef int   i32x4 __attribute__((ext_vector_type(4)));
typedef unsigned u32;

#define BARRIER() __builtin_amdgcn_s_barrier()
#define LGKM0()   __builtin_amdgcn_s_waitcnt(0xC07F)
#define SFENCE()  __builtin_amdgcn_sched_barrier(0)

__device__ __forceinline__ u32 fbits(float f) { return __builtin_bit_cast(u32, f); }
__device__ __forceinline__ u32 pkrne(float lo, float hi) {
  u32 a = fbits(lo); a = a + 0x7fffu + ((a >> 16) & 1u);
  u32 b = fbits(hi); b = b + 0x7fffu + ((b >> 16) & 1u);
  return (b & 0xffff0000u) | (a >> 16);
}

// k-enum (R9): ch = k>>3, wv = k&7: t = ch>>4, c = ch&15, L = 4c + (t>>1),
// n = 8(t&1) + wv. B-frag S for (lane c, tile lt) = S_row[4c+lt].

// wt[m][k] = w[L(k)][m][n(k)]/32 (bf16), 64x1024 = 128KB
__global__ void prep_wt(const float* __restrict__ w, unsigned short* __restrict__ wt) {
  int idx = blockIdx.x * 256 + threadIdx.x;
  int m = idx >> 10, k = idx & 1023;
  int ch = k >> 3, wv = k & 7, t = ch >> 4, cc = ch & 15;
  int l = (cc << 2) + (t >> 1), n = ((t & 1) << 3) + wv;
  u32 u = fbits(w[l * 1024 + m * 16 + n] * 0.03125f);
  wt[idx] = (unsigned short)((u + 0x7fffu + ((u >> 16) & 1u)) >> 16);
}

// nb[row][l] = bf16(nodes[row][l]) RNE (bit-identical to in-kernel conversion)
__global__ void prep_nb(const float* __restrict__ nodes, unsigned short* __restrict__ nb) {
  int idx = blockIdx.x * 256 + threadIdx.x;       // 262144 threads
  const float4* p = (const float4*)nodes + ((size_t)idx << 1);
  float4 a = p[0], b = p[1];
  uint4 o{pkrne(a.x, a.y), pkrne(a.z, a.w), pkrne(b.x, b.y), pkrne(b.z, b.w)};
  *((uint4*)nb + idx) = o;
}

__device__ __forceinline__ bf16x8 mk_bw(const float* wp) {
  float v[8];
  #pragma unroll
  for (int i = 0; i < 8; ++i) v[i] = wp[i] * 0.03125f;
  uint4 pk{pkrne(v[0], v[1]), pkrne(v[2], v[3]), pkrne(v[4], v[5]), pkrne(v[6], v[7])};
  return __builtin_bit_cast(bf16x8, pk);
}

// ============================================================================
// R18 = R17 RESUBMIT (R11 bench was an infra failure: "MI355X container
// failed twice" — no kernel signal; do not mutate the experiment on noise).
// Session ledger:
//  R6 (48us) / R10 (46.3us, +NT hints): 256-thr fused, wt->VGPR, DOUBLE-buf
//    64KB LDS, 2 WGs/CU = 8 waves. Model (fits R2-R10): time ~
//    sum(lines x latency)/C, C ~ 5-8 outstanding lines PER WAVE. Every round
//    since R6 moved traffic (lines, bytes, latency class); NONE moved C.
//  R7-R9: 512-thr K-split dead (toolchain caps 512-thr MFMA kernels at 128
//    VGPR regardless of knob; 28MB scratch).
//  R17/R18: raise C by +50% waves, keeping the verified R10 wave-code
//    identical:
//    (1) SINGLE 32KB G-buffer (extra barrier per tile; SE gathers still
//        overlap B); LDS now admits 5 WGs.
//    (2) 2 tiles/WG, grid 1024 -> 4 WGs/CU of work, 3 resident.
//    (3) launch_bounds (256,3) -> VGPR cap 170 >= measured liveness 168
//        (the proven-spill-free config of R0-R4).
//    Spill watch: WRITE_SIZE must stay ~10.6MB (NT-store level).
// ============================================================================
__global__ __launch_bounds__(256, 3)
void mp_fused(const int* __restrict__ nlist, const float* __restrict__ edges,
              const unsigned short* __restrict__ wt, const unsigned short* __restrict__ nb,
              float* __restrict__ out) {
  __shared__ u32 g_lds[16 * 512];   // 32 KB: SINGLE G-buffer

  const int tid = threadIdx.x;
  const int lane = tid & 63;
  const int wid = __builtin_amdgcn_readfirstlane(tid >> 6);
  const int q = lane >> 4, c = lane & 15;

  const int blk = blockIdx.x;                    // [0,1024)
  const int xcd = blk & 7;
  const int batch = xcd >> 2;
  const int ordinal = ((blk >> 3) << 2) + (xcd & 3);   // [0,512)
  const int wg0 = (batch << LOGN) + (ordinal << 5);    // 32 nodes per WG
  const unsigned short* __restrict__ nbb = nb + ((size_t)batch << 20);

  const int nd0 = wid << 2;
  const int m = (wid << 4) + c;

  // ---- wt slice -> 128 VGPRs, issued FIRST (oldest in vmcnt queue; L2-hit;
  // complete before first use via prologue's own vmcnt waits) ----
  bf16x8 wtreg[32];
  {
    const unsigned short* wb = wt + ((size_t)m << 10) + (q << 3);
    #pragma unroll
    for (int s = 0; s < 32; ++s) wtreg[s] = *(const bf16x8*)(wb + (s << 5));
  }

  i32x4 NI[4][2];      // neighbor indices for one tile
  uint2 U[4][8];       // bf16 S rows (CACHED - L2-resident gather table)
  float E[4][8];       // edge features (NT - once-through stream)

  auto issue_nl = [&](int g) {
    #pragma unroll
    for (int j = 0; j < 4; ++j) {
      const int* r = nlist + (((size_t)(g + nd0 + j)) << 5) + (q << 3);
      NI[j][0] = __builtin_nontemporal_load((const i32x4*)r);
      NI[j][1] = __builtin_nontemporal_load((const i32x4*)(r + 4));
    }
  };
  // gather S+E for nodes j0, j0+1 of tile with base g (32 loads)
  auto issue_se2 = [&](int g, int j0) {
    #pragma unroll
    for (int jj = 0; jj < 2; ++jj) {
      const int j = j0 + jj;
      const int ix[8] = {NI[j][0][0], NI[j][0][1], NI[j][0][2], NI[j][0][3],
                         NI[j][1][0], NI[j][1][1], NI[j][1][2], NI[j][1][3]};
      #pragma unroll
      for (int i = 0; i < 8; ++i)
        U[j][i] = *(const uint2*)(nbb + ((size_t)(u32)ix[i] << 6) + (c << 2));
      const float* ep = edges + (((size_t)(g + nd0 + j)) << 9) + (q << 7) + c;
      #pragma unroll
      for (int i = 0; i < 8; ++i)
        E[j][i] = __builtin_nontemporal_load(ep + (i << 4));
    }
  };
  // pack + 16 MFMA + ds_write tile into the (single) buffer
  auto consume_all = [&]() {
    #pragma unroll
    for (int j = 0; j < 4; ++j) {
      const int p = nd0 + j;
      uint4 apk{pkrne(E[j][0], E[j][1]), pkrne(E[j][2], E[j][3]),
                pkrne(E[j][4], E[j][5]), pkrne(E[j][6], E[j][7])};
      const bf16x8 af = __builtin_bit_cast(bf16x8, apk);
      #pragma unroll
      for (int lt = 0; lt < 4; ++lt) {
        const u32 sel = (lt & 1) ? 0x07060302u : 0x05040100u;
        u32 p0, p1, p2, p3;
        if (lt & 2) {
          p0 = __builtin_amdgcn_perm(U[j][1].y, U[j][0].y, sel);
          p1 = __builtin_amdgcn_perm(U[j][3].y, U[j][2].y, sel);
          p2 = __builtin_amdgcn_perm(U[j][5].y, U[j][4].y, sel);
          p3 = __builtin_amdgcn_perm(U[j][7].y, U[j][6].y, sel);
        } else {
          p0 = __builtin_amdgcn_perm(U[j][1].x, U[j][0].x, sel);
          p1 = __builtin_amdgcn_perm(U[j][3].x, U[j][2].x, sel);
          p2 = __builtin_amdgcn_perm(U[j][5].x, U[j][4].x, sel);
          p3 = __builtin_amdgcn_perm(U[j][7].x, U[j][6].x, sel);
        }
        uint4 spk{p0, p1, p2, p3};
        f32x4 acc{0.f, 0.f, 0.f, 0.f};
        acc = __builtin_amdgcn_mfma_f32_16x16x32_bf16(af,
                __builtin_bit_cast(bf16x8, spk), acc, 0, 0, 0);
        const u32 lo = pkrne(acc[0], acc[1]);
        const u32 hi = pkrne(acc[2], acc[3]);
        const int chunk = (c + (((lt << 1) + (q >> 1)) << 4)) ^ (p & 7);
        *(uint2*)&g_lds[(p << 9) + (chunk << 2) + ((q & 1) << 1)] = uint2{lo, hi};
      }
    }
  };
  auto store_out = [&](int g, const f32x4& ob) {
    #pragma unroll
    for (int r = 0; r < 4; ++r)
      __builtin_nontemporal_store(ob[r],
          out + ((size_t)(g + (q << 2) + r) << 6) + m);
  };

  const int g0 = wg0, g1 = wg0 + 16;

  // ---- prologue: tile 0 gathered + consumed -> buf ----
  issue_nl(g0);
  issue_se2(g0, 0);
  issue_se2(g0, 2);
  issue_nl(g1);
  consume_all();                  // -> buf (vmcnt waits also drain wtreg)
  LGKM0(); BARRIER();

  // ---- tile 0 B with tile 1 SE in flight ----
  issue_se2(g1, 0);
  SFENCE();
  f32x4 ob{0.f, 0.f, 0.f, 0.f};
  #pragma unroll
  for (int s = 0; s < 16; ++s) {
    uint4 ar = *(const uint4*)&g_lds[(c << 9) + ((((s << 2) + q) ^ (c & 7)) << 2)];
    ob = __builtin_amdgcn_mfma_f32_16x16x32_bf16(__builtin_bit_cast(bf16x8, ar),
                                                 wtreg[s], ob, 0, 0, 0);
  }
  issue_se2(g1, 2);
  SFENCE();
  #pragma unroll
  for (int s = 16; s < 32; ++s) {
    uint4 ar = *(const uint4*)&g_lds[(c << 9) + ((((s << 2) + q) ^ (c & 7)) << 2)];
    ob = __builtin_amdgcn_mfma_f32_16x16x32_bf16(__builtin_bit_cast(bf16x8, ar),
                                                 wtreg[s], ob, 0, 0, 0);
  }
  store_out(g0, ob);

  BARRIER();                      // all waves done READING buf
  consume_all();                  // tile 1 -> buf
  LGKM0(); BARRIER();

  // ---- tile 1 B ----
  {
    f32x4 o2{0.f, 0.f, 0.f, 0.f};
    #pragma unroll
    for (int s = 0; s < 32; ++s) {
      uint4 ar = *(const uint4*)&g_lds[(c << 9) + ((((s << 2) + q) ^ (c & 7)) << 2)];
      o2 = __builtin_amdgcn_mfma_f32_16x16x32_bf16(__builtin_bit_cast(bf16x8, ar),
                                                   wtreg[s], o2, 0, 0, 0);
    }
    store_out(g1, o2);
  }
}

// ============================================================================
// Fallback (no/partial workspace): R4's unfused kernel, grid 2048.
// ============================================================================
template <int MODE>
__global__ __launch_bounds__(256, 3)
void mp_kernel(const float* __restrict__ nodes, const int* __restrict__ nlist,
               const float* __restrict__ edges, const unsigned short* __restrict__ wt,
               const float* __restrict__ w, float* __restrict__ out) {
  __shared__ u32 g_lds[16 * 512];

  const int tid = threadIdx.x;
  const int lane = tid & 63;
  const int wid = __builtin_amdgcn_readfirstlane(tid >> 6);
  const int q = lane >> 4, c = lane & 15;

  const int blk = blockIdx.x;
  const int xcd = blk & 7;
  const int batch = xcd >> 2;
  const int ordinal = ((blk >> 3) << 2) + (xcd & 3);
  const int wg0 = (batch << LOGN) + (ordinal << 4);
  const float* __restrict__ nbase = nodes + ((size_t)batch << 20);

  const int nd0 = wid << 2;

  auto issue_nl = [&](int t, int4* ni) {
    const int* r = nlist + (((size_t)(wg0 + nd0 + t)) << 5) + (q << 3);
    ni[0] = *(const int4*)r;
    ni[1] = *(const int4*)(r + 4);
  };
  auto issue_se = [&](int t, const int4* ni, f32x4* R, float* Ee) {
    const int ix[8] = {ni[0].x, ni[0].y, ni[0].z, ni[0].w,
                       ni[1].x, ni[1].y, ni[1].z, ni[1].w};
    #pragma unroll
    for (int i = 0; i < 8; ++i)
      R[i] = *(const f32x4*)(nbase + ((size_t)(u32)ix[i] << 6) + (c << 2));
    const float* ep = edges + (((size_t)(wg0 + nd0 + t)) << 9) + (q << 7) + c;
    #pragma unroll
    for (int i = 0; i < 8; ++i) Ee[i] = ep[i << 4];
  };
  auto consume = [&](int p, const f32x4* R, const float* Ee) {
    uint4 apk{pkrne(Ee[0], Ee[1]), pkrne(Ee[2], Ee[3]),
              pkrne(Ee[4], Ee[5]), pkrne(Ee[6], Ee[7])};
    const bf16x8 af = __builtin_bit_cast(bf16x8, apk);
    #pragma unroll
    for (int lt = 0; lt < 4; ++lt) {
      uint4 spk{pkrne(R[0][lt], R[1][lt]), pkrne(R[2][lt], R[3][lt]),
                pkrne(R[4][lt], R[5][lt]), pkrne(R[6][lt], R[7][lt])};
      f32x4 acc{0.f, 0.f, 0.f, 0.f};
      acc = __builtin_amdgcn_mfma_f32_16x16x32_bf16(af,
              __builtin_bit_cast(bf16x8, spk), acc, 0, 0, 0);
      const u32 lo = pkrne(acc[0], acc[1]);
      const u32 hi = pkrne(acc[2], acc[3]);
      const int chunk = (c + (((lt << 1) + (q >> 1)) << 4)) ^ (p & 7);
      *(uint2*)&g_lds[(p << 9) + (chunk << 2) + ((q & 1) << 1)] = uint2{lo, hi};
    }
  };

  {
    int4 ni0[2], ni1[2];
    f32x4 R0[8], R1[8];
    float E0[8], E1[8];
    issue_nl(0, ni0);
    issue_nl(1, ni1);
    issue_se(0, ni0, R0, E0);
    issue_nl(2, ni0);
    issue_se(1, ni1, R1, E1);
    issue_nl(3, ni1);
    SFENCE();
    consume(nd0 + 0, R0, E0);
    issue_se(2, ni0, R0, E0);
    SFENCE();
    consume(nd0 + 1, R1, E1);
    issue_se(3, ni1, R1, E1);
    SFENCE();
    consume(nd0 + 2, R0, E0);
    consume(nd0 + 3, R1, E1);
  }

  LGKM0();
  BARRIER();

  const int m = (wid << 4) + c;
  f32x4 ob{0.f, 0.f, 0.f, 0.f};
  if constexpr (MODE >= 1) {
    const unsigned short* wb = wt + ((size_t)m << 10) + (q << 3);
    #pragma unroll 8
    for (int s = 0; s < 32; ++s) {
      uint4 ar = *(const uint4*)&g_lds[(c << 9) + ((((s << 2) + q) ^ (c & 7)) << 2)];
      ob = __builtin_amdgcn_mfma_f32_16x16x32_bf16(__builtin_bit_cast(bf16x8, ar),
                                                   *(const bf16x8*)(wb + (s << 5)),
                                                   ob, 0, 0, 0);
    }
  } else {
    #pragma unroll 4
    for (int s = 0; s < 32; ++s) {
      uint4 ar = *(const uint4*)&g_lds[(c << 9) + ((((s << 2) + q) ^ (c & 7)) << 2)];
      const int ch = (s << 2) + q;
      const int l = ((ch & 15) << 2) + (ch >> 5);
      const int n0 = ((ch >> 4) & 1) << 3;
      const float* wp = w + l * 1024 + m * 16 + n0;
      ob = __builtin_amdgcn_mfma_f32_16x16x32_bf16(__builtin_bit_cast(bf16x8, ar),
                                                   mk_bw(wp), ob, 0, 0, 0);
    }
  }

  #pragma unroll
  for (int r = 0; r < 4; ++r)
    out[((size_t)(wg0 + (q << 2) + r) << 6) + m] = ob[r];
}

extern "C" void kernel_launch(void* const* d_in, const int* in_sizes, int n_in,
                              void* d_out, int out_size, void* d_ws, size_t ws_size,
                              hipStream_t stream) {
  const float* nodes = (const float*)d_in[0];
  const int*   nlist = (const int*)d_in[1];
  const float* edges = (const float*)d_in[2];
  const float* w     = (const float*)d_in[3];
  float* out = (float*)d_out;

  const size_t WT_BYTES = 131072;               // 64x1024 bf16
  const size_t NB_BYTES = (size_t)1 << 22;      // 2x16384x64 bf16 = 4 MB

  if (ws_size >= WT_BYTES + NB_BYTES) {
    unsigned short* wt = (unsigned short*)d_ws;
    unsigned short* nb = wt + 65536;
    prep_wt<<<256, 256, 0, stream>>>(w, wt);
    prep_nb<<<1024, 256, 0, stream>>>(nodes, nb);
    mp_fused<<<1024, 256, 0, stream>>>(nlist, edges, wt, nb, out);
  } else if (ws_size >= WT_BYTES) {
    unsigned short* wt = (unsigned short*)d_ws;
    prep_wt<<<256, 256, 0, stream>>>(w, wt);
    mp_kernel<1><<<2048, 256, 0, stream>>>(nodes, nlist, edges, wt, w, out);
  } else {
    mp_kernel<0><<<2048, 256, 0, stream>>>(nodes, nlist, edges, nullptr, w, out);
  }
}